// Round 1
// baseline (327.329 us; speedup 1.0000x reference)
//
#include <hip/hip_runtime.h>
#include <hip/hip_bf16.h>
#include <cstdint>
#include <cstddef>

// B=4, T=4096, C=1024, d=64 causal self-attention head.
// Pipeline: pack_w (W -> bf16 B-frag layout) -> proj_gemm (q,k rowmajor bf16;
// v transposed [d][t] bf16) -> flash (per-wave 16-row Q tiles, fixed-max
// exp2 softmax, l via ones-MFMA, P transposed through wave-private LDS).

typedef __attribute__((ext_vector_type(8))) short short8;       // 8 x bf16 frag
typedef __attribute__((ext_vector_type(4))) float f32x4;
typedef __attribute__((ext_vector_type(4))) unsigned int uint4v;
typedef __attribute__((ext_vector_type(4))) unsigned short ushort4v;

#define MFMA16x16x32(A,B,C) __builtin_amdgcn_mfma_f32_16x16x32_bf16((A),(B),(C),0,0,0)

static __device__ __forceinline__ unsigned pack2_bf16(float f0, float f1){
  // round-half-up to bf16, pack two into one dword via v_perm
  unsigned u0 = __builtin_bit_cast(unsigned, f0) + 0x8000u;
  unsigned u1 = __builtin_bit_cast(unsigned, f1) + 0x8000u;
  return __builtin_amdgcn_perm(u1, u0, 0x07060302u);
}
static __device__ __forceinline__ unsigned short bf16u(float f){
  return (unsigned short)((__builtin_bit_cast(unsigned, f) + 0x8000u) >> 16);
}
static __device__ __forceinline__ short8 cvt8(f32x4 a, f32x4 b){
  union { unsigned u[4]; short8 s; } r;
  r.u[0] = pack2_bf16(a[0], a[1]);
  r.u[1] = pack2_bf16(a[2], a[3]);
  r.u[2] = pack2_bf16(b[0], b[1]);
  r.u[3] = pack2_bf16(b[2], b[3]);
  return r.s;
}
static __device__ __forceinline__ float fast_exp2(float x){
#if __has_builtin(__builtin_amdgcn_exp2f)
  return __builtin_amdgcn_exp2f(x);
#else
  float r; asm("v_exp_f32 %0, %1" : "=v"(r) : "v"(x)); return r;
#endif
}
static __device__ __forceinline__ float fast_rcp(float x){
#if __has_builtin(__builtin_amdgcn_rcpf)
  return __builtin_amdgcn_rcpf(x);
#else
  float r; asm("v_rcp_f32 %0, %1" : "=v"(r) : "v"(x)); return r;
#endif
}

// ---------------------------------------------------------------------------
// Kernel 0: pack W[1024][64] fp32 -> bf16 B-fragment layout.
// Layout: Wp[p][cc][nf][lane][8], lane=(qd,l): element j = W[cc*32+qd*8+j][nf*16+l]
// ---------------------------------------------------------------------------
__global__ __launch_bounds__(256) void pack_w(
    const float* __restrict__ Wq, const float* __restrict__ Wk,
    const float* __restrict__ Wv, unsigned short* __restrict__ Wp)
{
  int t = blockIdx.x * 256 + threadIdx.x;      // 3*32*4*64 = 24576 threads
  int lane = t & 63, nf = (t >> 6) & 3, cc = (t >> 8) & 31, p = t >> 13;
  int qd = lane >> 4, l = lane & 15;
  const float* W = (p == 0) ? Wq : ((p == 1) ? Wk : Wv);
  const float* src = W + (size_t)(cc * 32 + qd * 8) * 64 + nf * 16 + l;
  uint4v u;
  #pragma unroll
  for (int j = 0; j < 4; ++j)
    u[j] = pack2_bf16(src[(2 * j) * 64], src[(2 * j + 1) * 64]);
  *(uint4v*)(Wp + (size_t)t * 8) = u;
}

// ---------------------------------------------------------------------------
// Kernel 1: projections. grid (256, 3), block 128 (2 waves x 32 rows).
// p=0: q rowmajor, p=1: k rowmajor, p=2: v transposed vt[b][d][t].
// ---------------------------------------------------------------------------
__global__ __launch_bounds__(128) void proj_gemm(
    const float* __restrict__ Qx, const float* __restrict__ Kx, const float* __restrict__ Vx,
    const float* __restrict__ bqp, const float* __restrict__ bkp, const float* __restrict__ bvp,
    const unsigned short* __restrict__ Wp,
    unsigned short* __restrict__ qb, unsigned short* __restrict__ kb,
    unsigned short* __restrict__ vt)
{
  const int tid = threadIdx.x;
  const int lane = tid & 63, wid = tid >> 6;
  const int qd = lane >> 4, l = lane & 15;
  const int p = blockIdx.y;
  const float* X = (p == 0) ? Qx : ((p == 1) ? Kx : Vx);
  const float* bias = (p == 0) ? bqp : ((p == 1) ? bkp : bvp);
  const unsigned short* W = Wp + (size_t)p * 65536;

  const int row0 = blockIdx.x * 64 + wid * 32;
  const float* xa0 = X + (size_t)(row0 + l) * 1024 + qd * 8;   // m-tile 0
  const float* xa1 = xa0 + 16 * 1024;                          // m-tile 1
  const unsigned short* wb = W + (size_t)lane * 8;

  f32x4 acc[2][4];
  #pragma unroll
  for (int mt = 0; mt < 2; ++mt)
    #pragma unroll
    for (int nf = 0; nf < 4; ++nf) acc[mt][nf] = (f32x4){0.f, 0.f, 0.f, 0.f};

  #pragma unroll 2
  for (int cc = 0; cc < 32; ++cc){
    f32x4 a0l = *(const f32x4*)(xa0 + cc * 32);
    f32x4 a0h = *(const f32x4*)(xa0 + cc * 32 + 4);
    f32x4 a1l = *(const f32x4*)(xa1 + cc * 32);
    f32x4 a1h = *(const f32x4*)(xa1 + cc * 32 + 4);
    const unsigned short* wc = wb + (size_t)cc * 2048;
    short8 b0 = *(const short8*)(wc);
    short8 b1 = *(const short8*)(wc + 512);
    short8 b2 = *(const short8*)(wc + 1024);
    short8 b3 = *(const short8*)(wc + 1536);
    short8 a0 = cvt8(a0l, a0h);
    short8 a1 = cvt8(a1l, a1h);
    acc[0][0] = MFMA16x16x32(a0, b0, acc[0][0]);
    acc[0][1] = MFMA16x16x32(a0, b1, acc[0][1]);
    acc[0][2] = MFMA16x16x32(a0, b2, acc[0][2]);
    acc[0][3] = MFMA16x16x32(a0, b3, acc[0][3]);
    acc[1][0] = MFMA16x16x32(a1, b0, acc[1][0]);
    acc[1][1] = MFMA16x16x32(a1, b1, acc[1][1]);
    acc[1][2] = MFMA16x16x32(a1, b2, acc[1][2]);
    acc[1][3] = MFMA16x16x32(a1, b3, acc[1][3]);
  }

  if (p == 2){
    // vt[b][d][t], pack 4 consecutive t (C rows r=0..3) into one 8B store
    #pragma unroll
    for (int mt = 0; mt < 2; ++mt){
      int tg = row0 + mt * 16 + qd * 4;
      int b = tg >> 12, tl = tg & 4095;
      #pragma unroll
      for (int nf = 0; nf < 4; ++nf){
        float bb = bias[nf * 16 + l];
        ushort4v pk;
        #pragma unroll
        for (int r = 0; r < 4; ++r) pk[r] = bf16u(acc[mt][nf][r] + bb);
        *(ushort4v*)(vt + ((size_t)b * 64 + nf * 16 + l) * 4096 + tl) = pk;
      }
    }
  } else {
    unsigned short* o = (p == 0) ? qb : kb;
    #pragma unroll
    for (int mt = 0; mt < 2; ++mt)
      #pragma unroll
      for (int nf = 0; nf < 4; ++nf){
        float bb = bias[nf * 16 + l];
        #pragma unroll
        for (int r = 0; r < 4; ++r){
          int row = row0 + mt * 16 + qd * 4 + r;
          o[(size_t)row * 64 + nf * 16 + l] = bf16u(acc[mt][nf][r] + bb);
        }
      }
  }
}

// ---------------------------------------------------------------------------
// Kernel 2: causal flash attention. grid 256, block 256 (4 waves).
// wave = (batch = wid, tile = 255 - blockIdx.x), 16 q-rows per wave.
// Fixed-max softmax: P = exp2(s * log2e/8) (scores bounded ~ +-9 -> safe),
// row-sums via MFMA with ones-B. P C-layout -> A-layout via wave-private LDS.
// ---------------------------------------------------------------------------
#define K1 0.18033688011112042f   // log2(e)/sqrt(64)

__global__ __launch_bounds__(256) void flash(
    const unsigned short* __restrict__ qb, const unsigned short* __restrict__ kb,
    const unsigned short* __restrict__ vt, float* __restrict__ out)
{
  __shared__ unsigned short pbuf[4][16 * 40];    // stride 40 -> 16B-aligned rows
  const int tid = threadIdx.x;
  const int lane = tid & 63, wid = tid >> 6;
  const int qd = lane >> 4, l = lane & 15;
  const int batch = wid;
  const int tile = 255 - (int)blockIdx.x;        // descending work for balance
  const int q0 = tile * 16;
  const int kvend = q0 + 16;

  const unsigned short* qrow = qb + ((size_t)(batch * 4096 + q0 + l)) * 64 + qd * 8;
  short8 Qf0 = *(const short8*)(qrow);
  short8 Qf1 = *(const short8*)(qrow + 32);

  const unsigned short* kbase = kb + (size_t)batch * 4096 * 64;
  const unsigned short* vbase = vt + (size_t)batch * 64 * 4096;

  const f32x4 Zc = (f32x4){0.f, 0.f, 0.f, 0.f};
  f32x4 Oc[4] = {Zc, Zc, Zc, Zc};
  f32x4 Lacc = Zc;
  short8 onesf;
  #pragma unroll
  for (int i = 0; i < 8; ++i) onesf[i] = (short)0x3F80;   // bf16 1.0

  unsigned short* pw = &pbuf[wid][0];
  unsigned short* pwr = pw + qd * 160 + l;                 // write: row qd*4+r, col l(+16)
  const unsigned short* prd = pw + l * 40 + qd * 8;        // read: row l, cols qd*8..+7

#define FLASH_BODY(CUR, NXT, KV0)                                              \
  do {                                                                         \
    int kvn_ = (KV0) + 32; if (kvn_ >= kvend) kvn_ = 0;                        \
    const unsigned short* kp_ = kbase + (size_t)(kvn_ + l) * 64 + qd * 8;      \
    NXT[0] = *(const short8*)(kp_);                                            \
    NXT[1] = *(const short8*)(kp_ + 32);                                       \
    NXT[2] = *(const short8*)(kp_ + 1024);                                     \
    NXT[3] = *(const short8*)(kp_ + 1056);                                     \
    const unsigned short* vp_ = vbase + (size_t)l * 4096 + kvn_ + qd * 8;      \
    NXT[4] = *(const short8*)(vp_);                                            \
    NXT[5] = *(const short8*)(vp_ + 16 * 4096);                                \
    NXT[6] = *(const short8*)(vp_ + 32 * 4096);                                \
    NXT[7] = *(const short8*)(vp_ + 48 * 4096);                                \
    f32x4 s0_ = MFMA16x16x32(Qf0, CUR[0], Zc);                                 \
    s0_ = MFMA16x16x32(Qf1, CUR[1], s0_);                                      \
    f32x4 s1_ = MFMA16x16x32(Qf0, CUR[2], Zc);                                 \
    s1_ = MFMA16x16x32(Qf1, CUR[3], s1_);                                      \
    float p0_[4], p1_[4];                                                      \
    _Pragma("unroll")                                                          \
    for (int r = 0; r < 4; ++r){                                               \
      p0_[r] = fast_exp2(s0_[r] * K1);                                         \
      p1_[r] = fast_exp2(s1_[r] * K1);                                         \
    }                                                                          \
    if ((KV0) + 31 > q0){                                                      \
      _Pragma("unroll")                                                        \
      for (int r = 0; r < 4; ++r){                                             \
        int q_ = q0 + qd * 4 + r;                                              \
        if ((KV0) + l > q_) p0_[r] = 0.f;                                      \
        if ((KV0) + 16 + l > q_) p1_[r] = 0.f;                                 \
      }                                                                        \
    }                                                                          \
    _Pragma("unroll")                                                          \
    for (int r = 0; r < 4; ++r){                                               \
      pwr[r * 40] = bf16u(p0_[r]);                                             \
      pwr[r * 40 + 16] = bf16u(p1_[r]);                                        \
    }                                                                          \
    short8 Pf_ = *(const short8*)(prd);                                        \
    Lacc = MFMA16x16x32(Pf_, onesf, Lacc);                                     \
    Oc[0] = MFMA16x16x32(Pf_, CUR[4], Oc[0]);                                  \
    Oc[1] = MFMA16x16x32(Pf_, CUR[5], Oc[1]);                                  \
    Oc[2] = MFMA16x16x32(Pf_, CUR[6], Oc[2]);                                  \
    Oc[3] = MFMA16x16x32(Pf_, CUR[7], Oc[3]);                                  \
  } while (0)

  short8 bufA[8], bufB[8];
  { // prologue: load chunk kv0 = 0
    const unsigned short* kp_ = kbase + (size_t)l * 64 + qd * 8;
    bufA[0] = *(const short8*)(kp_);
    bufA[1] = *(const short8*)(kp_ + 32);
    bufA[2] = *(const short8*)(kp_ + 1024);
    bufA[3] = *(const short8*)(kp_ + 1056);
    const unsigned short* vp_ = vbase + (size_t)l * 4096 + qd * 8;
    bufA[4] = *(const short8*)(vp_);
    bufA[5] = *(const short8*)(vp_ + 16 * 4096);
    bufA[6] = *(const short8*)(vp_ + 32 * 4096);
    bufA[7] = *(const short8*)(vp_ + 48 * 4096);
  }
  int kv0 = 0;
  for (;;){
    FLASH_BODY(bufA, bufB, kv0);
    kv0 += 32; if (kv0 >= kvend) break;
    FLASH_BODY(bufB, bufA, kv0);
    kv0 += 32; if (kv0 >= kvend) break;
  }
#undef FLASH_BODY

  float inv[4];
  #pragma unroll
  for (int r = 0; r < 4; ++r) inv[r] = fast_rcp(Lacc[r]);
  float* ob = out + ((size_t)(batch * 4096 + q0 + qd * 4)) * 64 + l;
  #pragma unroll
  for (int nf = 0; nf < 4; ++nf)
    #pragma unroll
    for (int r = 0; r < 4; ++r)
      ob[(size_t)r * 64 + nf * 16] = Oc[nf][r] * inv[r];
}

// ---------------------------------------------------------------------------
extern "C" void kernel_launch(void* const* d_in, const int* in_sizes, int n_in,
                              void* d_out, int out_size, void* d_ws, size_t ws_size,
                              hipStream_t stream)
{
  const float* Q  = (const float*)d_in[0];
  const float* K  = (const float*)d_in[1];
  const float* V  = (const float*)d_in[2];
  const float* Wq = (const float*)d_in[3];
  const float* bq = (const float*)d_in[4];
  const float* Wk = (const float*)d_in[5];
  const float* bk = (const float*)d_in[6];
  const float* Wv = (const float*)d_in[7];
  const float* bv = (const float*)d_in[8];
  float* out = (float*)d_out;

  // workspace: qb(2MB) kb(2MB) vt(2MB) Wp(384KB)
  unsigned short* qb   = (unsigned short*)d_ws;
  unsigned short* kbuf = qb + (size_t)16384 * 64;
  unsigned short* vtp  = kbuf + (size_t)16384 * 64;
  unsigned short* Wp   = vtp + (size_t)16384 * 64;

  pack_w<<<96, 256, 0, stream>>>(Wq, Wk, Wv, Wp);
  proj_gemm<<<dim3(256, 3), 128, 0, stream>>>(Q, K, V, bq, bk, bv, Wp, qb, kbuf, vtp);
  flash<<<256, 256, 0, stream>>>(qb, kbuf, vtp, out);
}

// Round 2
// 299.965 us; speedup vs baseline: 1.0912x; 1.0912x over previous
//
#include <hip/hip_runtime.h>
#include <hip/hip_bf16.h>
#include <cstdint>
#include <cstddef>

// B=4, T=4096, C=1024, d=64 causal self-attention head.
// R2: split-KV flash (fixed-max softmax => partials sum exactly) with
// atomicAdd fp32 accumulation into zeroed out + L, then normalize.
// proj_gemm restructured to 16-row waves (12 waves/CU) for HBM latency hiding.

typedef __attribute__((ext_vector_type(8))) short short8;       // 8 x bf16 frag
typedef __attribute__((ext_vector_type(4))) float f32x4;
typedef __attribute__((ext_vector_type(4))) unsigned int uint4v;
typedef __attribute__((ext_vector_type(4))) unsigned short ushort4v;

#define MFMA16x16x32(A,B,C) __builtin_amdgcn_mfma_f32_16x16x32_bf16((A),(B),(C),0,0,0)

static __device__ __forceinline__ unsigned pack2_bf16(float f0, float f1){
  unsigned u0 = __builtin_bit_cast(unsigned, f0) + 0x8000u;
  unsigned u1 = __builtin_bit_cast(unsigned, f1) + 0x8000u;
  return __builtin_amdgcn_perm(u1, u0, 0x07060302u);
}
static __device__ __forceinline__ unsigned short bf16u(float f){
  return (unsigned short)((__builtin_bit_cast(unsigned, f) + 0x8000u) >> 16);
}
static __device__ __forceinline__ short8 cvt8(f32x4 a, f32x4 b){
  union { unsigned u[4]; short8 s; } r;
  r.u[0] = pack2_bf16(a[0], a[1]);
  r.u[1] = pack2_bf16(a[2], a[3]);
  r.u[2] = pack2_bf16(b[0], b[1]);
  r.u[3] = pack2_bf16(b[2], b[3]);
  return r.s;
}
static __device__ __forceinline__ float fast_exp2(float x){
  float r; asm("v_exp_f32 %0, %1" : "=v"(r) : "v"(x)); return r;
}
static __device__ __forceinline__ float fast_rcp(float x){
  float r; asm("v_rcp_f32 %0, %1" : "=v"(r) : "v"(x)); return r;
}

// ---------------------------------------------------------------------------
// Kernel 0: pack W fp32 -> bf16 B-fragment layout; also zero out (4MB) + L.
// Wp[p][cc][nf][lane][8], lane=(qd,l): elem j = W[cc*32+qd*8+j][nf*16+l]
// ---------------------------------------------------------------------------
__global__ __launch_bounds__(256) void pack_w(
    const float* __restrict__ Wq, const float* __restrict__ Wk,
    const float* __restrict__ Wv, unsigned short* __restrict__ Wp,
    float* __restrict__ out, float* __restrict__ Lbuf)
{
  int t = blockIdx.x * 256 + threadIdx.x;      // 256 blocks x 256 = 65536 thr
  if (t < 24576){                               // 3*32*4*64 pack jobs
    int lane = t & 63, nf = (t >> 6) & 3, cc = (t >> 8) & 31, p = t >> 13;
    int qd = lane >> 4, l = lane & 15;
    const float* W = (p == 0) ? Wq : ((p == 1) ? Wk : Wv);
    const float* src = W + (size_t)(cc * 32 + qd * 8) * 64 + nf * 16 + l;
    uint4v u;
    #pragma unroll
    for (int j = 0; j < 4; ++j)
      u[j] = pack2_bf16(src[(2 * j) * 64], src[(2 * j + 1) * 64]);
    *(uint4v*)(Wp + (size_t)t * 8) = u;
  }
  // grid-stride zero: out = 262144 f32x4, L = 4096 f32x4
  const f32x4 z = (f32x4){0.f, 0.f, 0.f, 0.f};
  f32x4* o4 = (f32x4*)out;
  f32x4* l4 = (f32x4*)Lbuf;
  for (int i = t; i < 262144 + 4096; i += 65536){
    if (i < 262144) o4[i] = z;
    else l4[i - 262144] = z;
  }
}

// ---------------------------------------------------------------------------
// Kernel 1: projections. grid (256, 3), block 256 (4 waves x 16 rows).
// 3072 waves = 12 waves/CU -> enough outstanding loads for HBM latency.
// p=0: q rowmajor, p=1: k rowmajor, p=2: v transposed vt[b][d][t].
// ---------------------------------------------------------------------------
__global__ __launch_bounds__(256) void proj_gemm(
    const float* __restrict__ Qx, const float* __restrict__ Kx, const float* __restrict__ Vx,
    const float* __restrict__ bqp, const float* __restrict__ bkp, const float* __restrict__ bvp,
    const unsigned short* __restrict__ Wp,
    unsigned short* __restrict__ qb, unsigned short* __restrict__ kb,
    unsigned short* __restrict__ vt)
{
  const int tid = threadIdx.x;
  const int lane = tid & 63, wid = tid >> 6;
  const int qd = lane >> 4, l = lane & 15;
  const int p = blockIdx.y;
  const float* X = (p == 0) ? Qx : ((p == 1) ? Kx : Vx);
  const float* bias = (p == 0) ? bqp : ((p == 1) ? bkp : bvp);
  const unsigned short* W = Wp + (size_t)p * 65536;

  const int row0 = blockIdx.x * 64 + wid * 16;
  const float* xa = X + (size_t)(row0 + l) * 1024 + qd * 8;
  const unsigned short* wb = W + (size_t)lane * 8;

  f32x4 acc[4];
  #pragma unroll
  for (int nf = 0; nf < 4; ++nf) acc[nf] = (f32x4){0.f, 0.f, 0.f, 0.f};

  #pragma unroll 4
  for (int cc = 0; cc < 32; ++cc){
    f32x4 al = *(const f32x4*)(xa + cc * 32);
    f32x4 ah = *(const f32x4*)(xa + cc * 32 + 4);
    const unsigned short* wc = wb + (size_t)cc * 2048;
    short8 b0 = *(const short8*)(wc);
    short8 b1 = *(const short8*)(wc + 512);
    short8 b2 = *(const short8*)(wc + 1024);
    short8 b3 = *(const short8*)(wc + 1536);
    short8 a = cvt8(al, ah);
    acc[0] = MFMA16x16x32(a, b0, acc[0]);
    acc[1] = MFMA16x16x32(a, b1, acc[1]);
    acc[2] = MFMA16x16x32(a, b2, acc[2]);
    acc[3] = MFMA16x16x32(a, b3, acc[3]);
  }

  if (p == 2){
    int tg = row0 + qd * 4;
    int b = tg >> 12, tl = tg & 4095;
    #pragma unroll
    for (int nf = 0; nf < 4; ++nf){
      float bb = bias[nf * 16 + l];
      ushort4v pk;
      #pragma unroll
      for (int r = 0; r < 4; ++r) pk[r] = bf16u(acc[nf][r] + bb);
      *(ushort4v*)(vt + ((size_t)b * 64 + nf * 16 + l) * 4096 + tl) = pk;
    }
  } else {
    unsigned short* o = (p == 0) ? qb : kb;
    #pragma unroll
    for (int nf = 0; nf < 4; ++nf){
      float bb = bias[nf * 16 + l];
      #pragma unroll
      for (int r = 0; r < 4; ++r){
        int row = row0 + qd * 4 + r;
        o[(size_t)row * 64 + nf * 16 + l] = bf16u(acc[nf][r] + bb);
      }
    }
  }
}

// ---------------------------------------------------------------------------
// Kernel 2: split-KV causal flash. grid 1152 blocks x 4 waves (wave = batch).
// Job j -> (tile t, segment s): group g = t/32 has g+1 segments of 512 kv.
// Fixed-max softmax partials sum exactly -> atomicAdd into out/L.
// ---------------------------------------------------------------------------
#define K1 0.18033688011112042f   // log2(e)/sqrt(64)

__global__ __launch_bounds__(256) void flash_split(
    const unsigned short* __restrict__ qb, const unsigned short* __restrict__ kb,
    const unsigned short* __restrict__ vt, float* __restrict__ out,
    float* __restrict__ Lbuf)
{
  __shared__ unsigned short pbuf[4][16 * 40];
  const int tid = threadIdx.x;
  const int lane = tid & 63, wid = tid >> 6;
  const int qd = lane >> 4, l = lane & 15;
  const int batch = wid;

  // decode job: reversed so long (full-segment) jobs dispatch first
  int j = 1151 - (int)blockIdx.x;
  int g = 0;
  while (j >= 16 * (g + 1) * (g + 2)) ++g;          // g in 0..7
  int r0 = j - 16 * g * (g + 1);
  int tq = r0 / (g + 1);
  const int t = 32 * g + tq;
  const int s = r0 - tq * (g + 1);
  const int q0 = t * 16;
  const int kvstart = s * 512;
  const int kvend = min(512 * (s + 1), q0 + 16);

  const unsigned short* qrow = qb + ((size_t)(batch * 4096 + q0 + l)) * 64 + qd * 8;
  short8 Qf0 = *(const short8*)(qrow);
  short8 Qf1 = *(const short8*)(qrow + 32);

  const unsigned short* kbase = kb + (size_t)batch * 4096 * 64;
  const unsigned short* vbase = vt + (size_t)batch * 64 * 4096;

  const f32x4 Zc = (f32x4){0.f, 0.f, 0.f, 0.f};
  f32x4 Oc[4] = {Zc, Zc, Zc, Zc};
  f32x4 Lacc = Zc;
  short8 onesf;
  #pragma unroll
  for (int i = 0; i < 8; ++i) onesf[i] = (short)0x3F80;   // bf16 1.0

  unsigned short* pw = &pbuf[wid][0];
  unsigned short* pwr = pw + qd * 160 + l;
  const unsigned short* prd = pw + l * 40 + qd * 8;

#define FLASH_BODY(CUR, NXT, KV0)                                              \
  do {                                                                         \
    int kvn_ = (KV0) + 32; if (kvn_ >= kvend) kvn_ = kvstart;                  \
    const unsigned short* kp_ = kbase + (size_t)(kvn_ + l) * 64 + qd * 8;      \
    NXT[0] = *(const short8*)(kp_);                                            \
    NXT[1] = *(const short8*)(kp_ + 32);                                       \
    NXT[2] = *(const short8*)(kp_ + 1024);                                     \
    NXT[3] = *(const short8*)(kp_ + 1056);                                     \
    const unsigned short* vp_ = vbase + (size_t)l * 4096 + kvn_ + qd * 8;      \
    NXT[4] = *(const short8*)(vp_);                                            \
    NXT[5] = *(const short8*)(vp_ + 16 * 4096);                                \
    NXT[6] = *(const short8*)(vp_ + 32 * 4096);                                \
    NXT[7] = *(const short8*)(vp_ + 48 * 4096);                                \
    f32x4 s0_ = MFMA16x16x32(Qf0, CUR[0], Zc);                                 \
    s0_ = MFMA16x16x32(Qf1, CUR[1], s0_);                                      \
    f32x4 s1_ = MFMA16x16x32(Qf0, CUR[2], Zc);                                 \
    s1_ = MFMA16x16x32(Qf1, CUR[3], s1_);                                      \
    float p0_[4], p1_[4];                                                      \
    _Pragma("unroll")                                                          \
    for (int r = 0; r < 4; ++r){                                               \
      p0_[r] = fast_exp2(s0_[r] * K1);                                         \
      p1_[r] = fast_exp2(s1_[r] * K1);                                         \
    }                                                                          \
    if ((KV0) + 31 > q0){                                                      \
      _Pragma("unroll")                                                        \
      for (int r = 0; r < 4; ++r){                                             \
        int q_ = q0 + qd * 4 + r;                                              \
        if ((KV0) + l > q_) p0_[r] = 0.f;                                      \
        if ((KV0) + 16 + l > q_) p1_[r] = 0.f;                                 \
      }                                                                        \
    }                                                                          \
    _Pragma("unroll")                                                          \
    for (int r = 0; r < 4; ++r){                                               \
      pwr[r * 40] = bf16u(p0_[r]);                                             \
      pwr[r * 40 + 16] = bf16u(p1_[r]);                                        \
    }                                                                          \
    short8 Pf_ = *(const short8*)(prd);                                        \
    Lacc = MFMA16x16x32(Pf_, onesf, Lacc);                                     \
    Oc[0] = MFMA16x16x32(Pf_, CUR[4], Oc[0]);                                  \
    Oc[1] = MFMA16x16x32(Pf_, CUR[5], Oc[1]);                                  \
    Oc[2] = MFMA16x16x32(Pf_, CUR[6], Oc[2]);                                  \
    Oc[3] = MFMA16x16x32(Pf_, CUR[7], Oc[3]);                                  \
  } while (0)

  short8 bufA[8], bufB[8];
  { // prologue: load chunk kvstart
    const unsigned short* kp_ = kbase + (size_t)(kvstart + l) * 64 + qd * 8;
    bufA[0] = *(const short8*)(kp_);
    bufA[1] = *(const short8*)(kp_ + 32);
    bufA[2] = *(const short8*)(kp_ + 1024);
    bufA[3] = *(const short8*)(kp_ + 1056);
    const unsigned short* vp_ = vbase + (size_t)l * 4096 + kvstart + qd * 8;
    bufA[4] = *(const short8*)(vp_);
    bufA[5] = *(const short8*)(vp_ + 16 * 4096);
    bufA[6] = *(const short8*)(vp_ + 32 * 4096);
    bufA[7] = *(const short8*)(vp_ + 48 * 4096);
  }
  int kv0 = kvstart;
  for (;;){
    FLASH_BODY(bufA, bufB, kv0);
    kv0 += 32; if (kv0 >= kvend) break;
    FLASH_BODY(bufB, bufA, kv0);
    kv0 += 32; if (kv0 >= kvend) break;
  }
#undef FLASH_BODY

  // accumulate partials
  float* ob = out + ((size_t)(batch * 4096 + q0 + qd * 4)) * 64 + l;
  #pragma unroll
  for (int nf = 0; nf < 4; ++nf)
    #pragma unroll
    for (int r = 0; r < 4; ++r)
      atomicAdd(&ob[(size_t)r * 64 + nf * 16], Oc[nf][r]);
  if (l == 0){
    float* lb = Lbuf + batch * 4096 + q0 + qd * 4;
    #pragma unroll
    for (int r = 0; r < 4; ++r) atomicAdd(&lb[r], Lacc[r]);
  }
}

// ---------------------------------------------------------------------------
// Kernel 3: out[row][d] /= L[row]. 262144 f32x4 -> grid 1024 x 256.
// ---------------------------------------------------------------------------
__global__ __launch_bounds__(256) void normalize(
    float* __restrict__ out, const float* __restrict__ Lbuf)
{
  int idx = blockIdx.x * 256 + threadIdx.x;
  f32x4 v = ((f32x4*)out)[idx];
  float inv = fast_rcp(Lbuf[idx >> 4]);
  v[0] *= inv; v[1] *= inv; v[2] *= inv; v[3] *= inv;
  ((f32x4*)out)[idx] = v;
}

// ---------------------------------------------------------------------------
extern "C" void kernel_launch(void* const* d_in, const int* in_sizes, int n_in,
                              void* d_out, int out_size, void* d_ws, size_t ws_size,
                              hipStream_t stream)
{
  const float* Q  = (const float*)d_in[0];
  const float* K  = (const float*)d_in[1];
  const float* V  = (const float*)d_in[2];
  const float* Wq = (const float*)d_in[3];
  const float* bq = (const float*)d_in[4];
  const float* Wk = (const float*)d_in[5];
  const float* bk = (const float*)d_in[6];
  const float* Wv = (const float*)d_in[7];
  const float* bv = (const float*)d_in[8];
  float* out = (float*)d_out;

  // workspace: qb(2MB) kb(2MB) vt(2MB) Wp(384KB) L(64KB)
  unsigned short* qb   = (unsigned short*)d_ws;
  unsigned short* kbuf = qb + (size_t)16384 * 64;
  unsigned short* vtp  = kbuf + (size_t)16384 * 64;
  unsigned short* Wp   = vtp + (size_t)16384 * 64;
  float* Lbuf = (float*)(Wp + (size_t)3 * 65536);

  pack_w<<<256, 256, 0, stream>>>(Wq, Wk, Wv, Wp, out, Lbuf);
  proj_gemm<<<dim3(256, 3), 256, 0, stream>>>(Q, K, V, bq, bk, bv, Wp, qb, kbuf, vtp);
  flash_split<<<1152, 256, 0, stream>>>(qb, kbuf, vtp, out, Lbuf);
  normalize<<<1024, 256, 0, stream>>>(out, Lbuf);
}

// Round 3
// 253.125 us; speedup vs baseline: 1.2932x; 1.1851x over previous
//
#include <hip/hip_runtime.h>
#include <hip/hip_bf16.h>
#include <cstdint>
#include <cstddef>

// B=4, T=4096, C=1024, d=64 causal self-attention head.
// R3: flash restructured to block-cooperative LDS staging via
// global_load_lds (async, width 16) with XOR-swizzled slots; block =
// (batch, 64-row qtile, 512-kv seg), 4 waves share one K/V stream.
// Fixed-max softmax partials sum exactly -> atomicAdd + normalize.

typedef __attribute__((ext_vector_type(8))) short short8;       // 8 x bf16 frag
typedef __attribute__((ext_vector_type(4))) float f32x4;
typedef __attribute__((ext_vector_type(4))) unsigned int uint4v;
typedef __attribute__((ext_vector_type(4))) unsigned short ushort4v;
typedef unsigned short ushort;

#define MFMA16x16x32(A,B,C) __builtin_amdgcn_mfma_f32_16x16x32_bf16((A),(B),(C),0,0,0)

static __device__ __forceinline__ unsigned pack2_bf16(float f0, float f1){
  unsigned u0 = __builtin_bit_cast(unsigned, f0) + 0x8000u;
  unsigned u1 = __builtin_bit_cast(unsigned, f1) + 0x8000u;
  return __builtin_amdgcn_perm(u1, u0, 0x07060302u);
}
static __device__ __forceinline__ unsigned short bf16u(float f){
  return (unsigned short)((__builtin_bit_cast(unsigned, f) + 0x8000u) >> 16);
}
static __device__ __forceinline__ short8 cvt8(f32x4 a, f32x4 b){
  union { unsigned u[4]; short8 s; } r;
  r.u[0] = pack2_bf16(a[0], a[1]);
  r.u[1] = pack2_bf16(a[2], a[3]);
  r.u[2] = pack2_bf16(b[0], b[1]);
  r.u[3] = pack2_bf16(b[2], b[3]);
  return r.s;
}
static __device__ __forceinline__ float fast_exp2(float x){
  float r; asm("v_exp_f32 %0, %1" : "=v"(r) : "v"(x)); return r;
}
static __device__ __forceinline__ float fast_rcp(float x){
  float r; asm("v_rcp_f32 %0, %1" : "=v"(r) : "v"(x)); return r;
}
static __device__ __forceinline__ void gl_lds16(const ushort* g, ushort* l){
  __builtin_amdgcn_global_load_lds(
      (const __attribute__((address_space(1))) void*)g,
      (__attribute__((address_space(3))) void*)l, 16, 0, 0);
}

// ---------------------------------------------------------------------------
// Kernel 0: pack W fp32 -> bf16 B-fragment layout; also zero out (4MB) + L.
// ---------------------------------------------------------------------------
__global__ __launch_bounds__(256) void pack_w(
    const float* __restrict__ Wq, const float* __restrict__ Wk,
    const float* __restrict__ Wv, unsigned short* __restrict__ Wp,
    float* __restrict__ out, float* __restrict__ Lbuf)
{
  int t = blockIdx.x * 256 + threadIdx.x;      // 256 blocks x 256 = 65536 thr
  if (t < 24576){                               // 3*32*4*64 pack jobs
    int lane = t & 63, nf = (t >> 6) & 3, cc = (t >> 8) & 31, p = t >> 13;
    int qd = lane >> 4, l = lane & 15;
    const float* W = (p == 0) ? Wq : ((p == 1) ? Wk : Wv);
    const float* src = W + (size_t)(cc * 32 + qd * 8) * 64 + nf * 16 + l;
    uint4v u;
    #pragma unroll
    for (int j = 0; j < 4; ++j)
      u[j] = pack2_bf16(src[(2 * j) * 64], src[(2 * j + 1) * 64]);
    *(uint4v*)(Wp + (size_t)t * 8) = u;
  }
  const f32x4 z = (f32x4){0.f, 0.f, 0.f, 0.f};
  f32x4* o4 = (f32x4*)out;
  f32x4* l4 = (f32x4*)Lbuf;
  for (int i = t; i < 262144 + 4096; i += 65536){
    if (i < 262144) o4[i] = z;
    else l4[i - 262144] = z;
  }
}

// ---------------------------------------------------------------------------
// Kernel 1: projections. grid (256, 3), block 256 (4 waves x 16 rows).
// ---------------------------------------------------------------------------
__global__ __launch_bounds__(256) void proj_gemm(
    const float* __restrict__ Qx, const float* __restrict__ Kx, const float* __restrict__ Vx,
    const float* __restrict__ bqp, const float* __restrict__ bkp, const float* __restrict__ bvp,
    const unsigned short* __restrict__ Wp,
    unsigned short* __restrict__ qb, unsigned short* __restrict__ kb,
    unsigned short* __restrict__ vt)
{
  const int tid = threadIdx.x;
  const int lane = tid & 63, wid = tid >> 6;
  const int qd = lane >> 4, l = lane & 15;
  const int p = blockIdx.y;
  const float* X = (p == 0) ? Qx : ((p == 1) ? Kx : Vx);
  const float* bias = (p == 0) ? bqp : ((p == 1) ? bkp : bvp);
  const unsigned short* W = Wp + (size_t)p * 65536;

  const int row0 = blockIdx.x * 64 + wid * 16;
  const float* xa = X + (size_t)(row0 + l) * 1024 + qd * 8;
  const unsigned short* wb = W + (size_t)lane * 8;

  f32x4 acc[4];
  #pragma unroll
  for (int nf = 0; nf < 4; ++nf) acc[nf] = (f32x4){0.f, 0.f, 0.f, 0.f};

  #pragma unroll 4
  for (int cc = 0; cc < 32; ++cc){
    f32x4 al = *(const f32x4*)(xa + cc * 32);
    f32x4 ah = *(const f32x4*)(xa + cc * 32 + 4);
    const unsigned short* wc = wb + (size_t)cc * 2048;
    short8 b0 = *(const short8*)(wc);
    short8 b1 = *(const short8*)(wc + 512);
    short8 b2 = *(const short8*)(wc + 1024);
    short8 b3 = *(const short8*)(wc + 1536);
    short8 a = cvt8(al, ah);
    acc[0] = MFMA16x16x32(a, b0, acc[0]);
    acc[1] = MFMA16x16x32(a, b1, acc[1]);
    acc[2] = MFMA16x16x32(a, b2, acc[2]);
    acc[3] = MFMA16x16x32(a, b3, acc[3]);
  }

  if (p == 2){
    int tg = row0 + qd * 4;
    int b = tg >> 12, tl = tg & 4095;
    #pragma unroll
    for (int nf = 0; nf < 4; ++nf){
      float bb = bias[nf * 16 + l];
      ushort4v pk;
      #pragma unroll
      for (int r = 0; r < 4; ++r) pk[r] = bf16u(acc[nf][r] + bb);
      *(ushort4v*)(vt + ((size_t)b * 64 + nf * 16 + l) * 4096 + tl) = pk;
    }
  } else {
    unsigned short* o = (p == 0) ? qb : kb;
    #pragma unroll
    for (int nf = 0; nf < 4; ++nf){
      float bb = bias[nf * 16 + l];
      #pragma unroll
      for (int r = 0; r < 4; ++r){
        int row = row0 + qd * 4 + r;
        o[(size_t)row * 64 + nf * 16 + l] = bf16u(acc[nf][r] + bb);
      }
    }
  }
}

// ---------------------------------------------------------------------------
// Kernel 2: split-KV causal flash, block-cooperative LDS staging.
// grid 1152 = 4 batches x 288 jobs; block 256 = 4 waves, wave w owns
// q-rows [qt*64 + w*16, +16). K/V 64-kv chunks double-buffered in LDS,
// staged by global_load_lds w/ xor-swizzled slots (2-way banks on read).
// ---------------------------------------------------------------------------
#define K1 0.18033688011112042f   // log2(e)/sqrt(64)

__global__ __launch_bounds__(256) void flash_split(
    const ushort* __restrict__ qb, const ushort* __restrict__ kb,
    const ushort* __restrict__ vt, float* __restrict__ out,
    float* __restrict__ Lbuf)
{
  __shared__ ushort Ks[2][4096];      // [buf][kvrow(64) * 64], 8 slots/row, c^(r&7)
  __shared__ ushort Vs[2][4096];      // [buf][d(64) * 64kv], 8 slots/row, c^(d&7)
  __shared__ ushort pbuf[4][16 * 40];

  const int tid = threadIdx.x;
  const int lane = tid & 63, wid = tid >> 6;
  const int qd = lane >> 4, l = lane & 15;
  const int lw = l & 7;

  // job decode (reversed: heavy groups first); batch = bidx&3 pins to 2 XCDs
  int bidx = (int)blockIdx.x;
  const int batch = bidx & 3;
  int j = 287 - (bidx >> 2);
  int g = 0;
  while (j >= 4 * (g + 1) * (g + 2)) ++g;        // g in 0..7
  int j2 = j - 4 * g * (g + 1);
  int tq = j2 / (g + 1);
  int s = j2 - tq * (g + 1);
  const int q0b = (8 * g + tq) * 64;
  const int kvstart = s * 512;
  const int kvend = min(kvstart + 512, q0b + 64); // width multiple of 64
  const int q0w = q0b + wid * 16;

  const ushort* kbB = kb + (size_t)batch * 262144;
  const ushort* vtB = vt + (size_t)batch * 262144;

  const ushort* qrow = qb + ((size_t)(batch * 4096 + q0w + l)) * 64 + qd * 8;
  short8 Qf0 = *(const short8*)(qrow);
  short8 Qf1 = *(const short8*)(qrow + 32);

  const f32x4 Zc = (f32x4){0.f, 0.f, 0.f, 0.f};
  f32x4 Oc[4] = {Zc, Zc, Zc, Zc};
  f32x4 Lacc = Zc;
  short8 onesf;
  #pragma unroll
  for (int i = 0; i < 8; ++i) onesf[i] = (short)0x3F80;   // bf16 1.0

  ushort* pw = &pbuf[wid][0];
  ushort* pwr = pw + qd * 160 + l;
  const ushort* prd = pw + l * 40 + qd * 8;

  // staging: wave w -> K rows {w*8..+7, 32+w*8..+7}, V d-rows same; lane maps
  // slot c=lane&7 of row r=(lane>>3): global col = (c ^ (r&7))*8
#define STAGE(BB, KVC) do{                                                     \
    int r8_ = lane >> 3, sw_ = ((lane & 7) ^ r8_) << 3;                        \
    int rA_ = wid * 8 + r8_;                                                   \
    const ushort* gk_ = kbB + (size_t)((KVC) + rA_) * 64 + sw_;                \
    gl_lds16(gk_,            &Ks[BB][wid * 512]);                              \
    gl_lds16(gk_ + 32 * 64,  &Ks[BB][2048 + wid * 512]);                       \
    const ushort* gv_ = vtB + (size_t)rA_ * 4096 + (KVC) + sw_;                \
    gl_lds16(gv_,              &Vs[BB][wid * 512]);                            \
    gl_lds16(gv_ + 32 * 4096,  &Vs[BB][2048 + wid * 512]);                     \
  } while (0)

  // one 32-kv chunk: ROFF in {0,32} within the staged 64; KVG = global kv0
#define CHUNK(BB, ROFF, KVG) do{                                               \
    if ((KVG) < q0w + 16){                                                     \
      const ushort* KsB_ = &Ks[BB][0];                                         \
      const ushort* VsB_ = &Vs[BB][0];                                         \
      short8 k0_ = *(const short8*)(KsB_ + (l + (ROFF)) * 64 + ((qd ^ lw) << 3));        \
      short8 k1_ = *(const short8*)(KsB_ + (l + (ROFF)) * 64 + (((qd + 4) ^ lw) << 3));  \
      short8 k2_ = *(const short8*)(KsB_ + (l + 16 + (ROFF)) * 64 + ((qd ^ lw) << 3));   \
      short8 k3_ = *(const short8*)(KsB_ + (l + 16 + (ROFF)) * 64 + (((qd + 4) ^ lw) << 3)); \
      f32x4 s0_ = MFMA16x16x32(Qf0, k0_, Zc);                                  \
      s0_ = MFMA16x16x32(Qf1, k1_, s0_);                                       \
      f32x4 s1_ = MFMA16x16x32(Qf0, k2_, Zc);                                  \
      s1_ = MFMA16x16x32(Qf1, k3_, s1_);                                       \
      float p0_[4], p1_[4];                                                    \
      _Pragma("unroll")                                                        \
      for (int r = 0; r < 4; ++r){                                             \
        p0_[r] = fast_exp2(s0_[r] * K1);                                       \
        p1_[r] = fast_exp2(s1_[r] * K1);                                       \
      }                                                                        \
      if ((KVG) + 31 > q0w){                                                   \
        _Pragma("unroll")                                                      \
        for (int r = 0; r < 4; ++r){                                           \
          int q_ = q0w + qd * 4 + r;                                           \
          if ((KVG) + l > q_) p0_[r] = 0.f;                                    \
          if ((KVG) + 16 + l > q_) p1_[r] = 0.f;                               \
        }                                                                      \
      }                                                                        \
      _Pragma("unroll")                                                        \
      for (int r = 0; r < 4; ++r){                                             \
        pwr[r * 40] = bf16u(p0_[r]);                                           \
        pwr[r * 40 + 16] = bf16u(p1_[r]);                                      \
      }                                                                        \
      short8 Pf_ = *(const short8*)(prd);                                      \
      int vs_ = ((qd + ((ROFF) >> 3)) ^ lw) << 3;                              \
      short8 v0_ = *(const short8*)(VsB_ + (l     ) * 64 + vs_);               \
      short8 v1_ = *(const short8*)(VsB_ + (l + 16) * 64 + vs_);               \
      short8 v2_ = *(const short8*)(VsB_ + (l + 32) * 64 + vs_);               \
      short8 v3_ = *(const short8*)(VsB_ + (l + 48) * 64 + vs_);               \
      Lacc = MFMA16x16x32(Pf_, onesf, Lacc);                                   \
      Oc[0] = MFMA16x16x32(Pf_, v0_, Oc[0]);                                   \
      Oc[1] = MFMA16x16x32(Pf_, v1_, Oc[1]);                                   \
      Oc[2] = MFMA16x16x32(Pf_, v2_, Oc[2]);                                   \
      Oc[3] = MFMA16x16x32(Pf_, v3_, Oc[3]);                                   \
    }                                                                          \
  } while (0)

  const int nst = (kvend - kvstart) >> 6;     // 64-kv stages (1..8)
  STAGE(0, kvstart);
  __syncthreads();
  int kvc = kvstart;
  for (int it = 0; it < nst; ++it){
    int bb = it & 1;
    if (it + 1 < nst) STAGE(bb ^ 1, kvc + 64);   // async prefetch
    CHUNK(bb, 0, kvc);
    CHUNK(bb, 32, kvc + 32);
    __syncthreads();                              // drains prefetch + guards reuse
    kvc += 64;
  }
#undef STAGE
#undef CHUNK

  // accumulate partials
  float* ob = out + ((size_t)(batch * 4096 + q0w + qd * 4)) * 64 + l;
  #pragma unroll
  for (int nf = 0; nf < 4; ++nf)
    #pragma unroll
    for (int r = 0; r < 4; ++r)
      atomicAdd(&ob[(size_t)r * 64 + nf * 16], Oc[nf][r]);
  if (l == 0){
    float* lb = Lbuf + batch * 4096 + q0w + qd * 4;
    #pragma unroll
    for (int r = 0; r < 4; ++r) atomicAdd(&lb[r], Lacc[r]);
  }
}

// ---------------------------------------------------------------------------
// Kernel 3: out[row][d] /= L[row].
// ---------------------------------------------------------------------------
__global__ __launch_bounds__(256) void normalize(
    float* __restrict__ out, const float* __restrict__ Lbuf)
{
  int idx = blockIdx.x * 256 + threadIdx.x;
  f32x4 v = ((f32x4*)out)[idx];
  float inv = fast_rcp(Lbuf[idx >> 4]);
  v[0] *= inv; v[1] *= inv; v[2] *= inv; v[3] *= inv;
  ((f32x4*)out)[idx] = v;
}

// ---------------------------------------------------------------------------
extern "C" void kernel_launch(void* const* d_in, const int* in_sizes, int n_in,
                              void* d_out, int out_size, void* d_ws, size_t ws_size,
                              hipStream_t stream)
{
  const float* Q  = (const float*)d_in[0];
  const float* K  = (const float*)d_in[1];
  const float* V  = (const float*)d_in[2];
  const float* Wq = (const float*)d_in[3];
  const float* bq = (const float*)d_in[4];
  const float* Wk = (const float*)d_in[5];
  const float* bk = (const float*)d_in[6];
  const float* Wv = (const float*)d_in[7];
  const float* bv = (const float*)d_in[8];
  float* out = (float*)d_out;

  // workspace: qb(2MB) kb(2MB) vt(2MB) Wp(384KB) L(64KB)
  unsigned short* qb   = (unsigned short*)d_ws;
  unsigned short* kbuf = qb + (size_t)16384 * 64;
  unsigned short* vtp  = kbuf + (size_t)16384 * 64;
  unsigned short* Wp   = vtp + (size_t)16384 * 64;
  float* Lbuf = (float*)(Wp + (size_t)3 * 65536);

  pack_w<<<256, 256, 0, stream>>>(Wq, Wk, Wv, Wp, out, Lbuf);
  proj_gemm<<<dim3(256, 3), 256, 0, stream>>>(Q, K, V, bq, bk, bv, Wp, qb, kbuf, vtp);
  flash_split<<<1152, 256, 0, stream>>>(qb, kbuf, vtp, out, Lbuf);
  normalize<<<1024, 256, 0, stream>>>(out, Lbuf);
}